// Round 2
// baseline (1598.777 us; speedup 1.0000x reference)
//
#include <hip/hip_runtime.h>

#define RES 128
#define RES_V 129
#define N_VOX 400000

constexpr int N_VERTS = RES_V * RES_V * RES_V;   // 2146689
constexpr int N_CELLS = RES * RES * RES;         // 2097152
constexpr long VOUT_WORDS = (long)N_VERTS * 10;  // 21466890
constexpr long OUTW_WORDS = (long)N_CELLS * 21;  // 44040192
constexpr float SDF_BIAS = -1.0f / 128.0f;
constexpr float DEFORM_SCALE = (float)((1.0 - 1e-8) / 256.0);
constexpr float INV_RES = 1.0f / 128.0f;

// --- K0: initialize accumulators (no hipMemsetAsync: pure kernel nodes) ---
__global__ void init_kernel(float* __restrict__ vout,
                            float* __restrict__ cnts,
                            int* __restrict__ lastidx)
{
    long t = (long)blockIdx.x * blockDim.x + threadIdx.x;
    if (t < VOUT_WORDS) vout[t] = 0.0f;
    if (t < N_VERTS) cnts[t] = 0.0f;
    if (t < N_CELLS) lastidx[t] = -1;
}

// --- K1: scatter-add voxel corner attributes into vertex accumulators ---
__global__ void scatter_kernel(const int* __restrict__ coords,
                               const float* __restrict__ feats,
                               float* __restrict__ vout_accum,   // [N_VERTS*10]
                               float* __restrict__ cnts,         // [N_VERTS]
                               int* __restrict__ lastidx)        // [N_CELLS]
{
    int t = blockIdx.x * blockDim.x + threadIdx.x;
    if (t >= N_VOX * 8) return;
    int n = t >> 3;
    int c = t & 7;
    int cx = coords[n * 3 + 0];
    int cy = coords[n * 3 + 1];
    int cz = coords[n * 3 + 2];
    int dx = c & 1, dy = (c >> 1) & 1, dz = (c >> 2) & 1;
    int vid = ((cx + dx) * RES_V + (cy + dy)) * RES_V + (cz + dz);

    const float* f = feats + (long)n * 101;
    float v[10];
    v[0] = f[c];                                   // sdf (bias applied in finalize)
#pragma unroll
    for (int k = 0; k < 3; ++k) v[1 + k] = f[8 + 3 * c + k];    // deform
#pragma unroll
    for (int k = 0; k < 6; ++k) v[4 + k] = f[53 + 6 * c + k];   // color

    float* dst = vout_accum + (long)vid * 10;
#pragma unroll
    for (int j = 0; j < 10; ++j) atomicAdd(dst + j, v[j]);
    atomicAdd(cnts + vid, 1.0f);

    if (c == 0) {
        int cid = (cx * RES + cy) * RES + cz;
        atomicMax(lastidx + cid, n);   // numpy .at[].set last-write-wins
    }
}

// --- K2: finalize vertices in place: divide by count, tanh-deform lattice ---
__global__ void finalize_verts(float* __restrict__ vout,
                               const float* __restrict__ cnts)
{
    int vid = blockIdx.x * blockDim.x + threadIdx.x;
    if (vid >= N_VERTS) return;
    float inv = 1.0f / fmaxf(cnts[vid], 1.0f);
    float* p = vout + (long)vid * 10;
    float s[10];
#pragma unroll
    for (int j = 0; j < 10; ++j) s[j] = p[j] * inv;

    int rz = vid % RES_V;
    int tmp = vid / RES_V;
    int ry = tmp % RES_V;
    int rx = tmp / RES_V;

    float o[10];
    o[0] = (float)rx * INV_RES - 0.5f + DEFORM_SCALE * tanhf(s[1]);
    o[1] = (float)ry * INV_RES - 0.5f + DEFORM_SCALE * tanhf(s[2]);
    o[2] = (float)rz * INV_RES - 0.5f + DEFORM_SCALE * tanhf(s[3]);
    o[3] = s[0] + SDF_BIAS;
#pragma unroll
    for (int j = 0; j < 6; ++j) o[4 + j] = s[4 + j];
#pragma unroll
    for (int j = 0; j < 10; ++j) p[j] = o[j];
}

// --- K3: write weights grid, one thread per output element (coalesced) ---
// NOTE: this overwrites the outw tail where cnts lived — cnts was fully
// consumed by finalize_verts (strictly earlier in the stream), so no conflict.
__global__ void weights_fill(const float* __restrict__ feats,
                             const int* __restrict__ lastidx,
                             float* __restrict__ outw)           // [N_CELLS*21]
{
    long t = (long)blockIdx.x * blockDim.x + threadIdx.x;
    if (t >= OUTW_WORDS) return;
    int cid = (int)(t / 21);
    int j = (int)(t - (long)cid * 21);
    int li = lastidx[cid];
    float val = 0.0f;
    if (li >= 0) val = feats[(long)li * 101 + 32 + j];
    outw[t] = val;
}

extern "C" void kernel_launch(void* const* d_in, const int* in_sizes, int n_in,
                              void* d_out, int out_size, void* d_ws, size_t ws_size,
                              hipStream_t stream) {
    const int* coords = (const int*)d_in[0];
    const float* feats = (const float*)d_in[1];
    float* out = (float*)d_out;
    float* vout = out;                                  // [N_VERTS*10]
    float* outw = out + VOUT_WORDS;                     // [N_CELLS*21]

    // cnts lives in the TAIL of outw: consumed by finalize_verts before
    // weights_fill overwrites it. Only lastidx (8.39 MB) uses d_ws.
    float* cnts = outw + (OUTW_WORDS - N_VERTS);
    int* lastidx = (int*)d_ws;

    {
        long total = VOUT_WORDS;  // covers N_VERTS and N_CELLS ranges too
        init_kernel<<<(int)((total + 255) / 256), 256, 0, stream>>>(vout, cnts, lastidx);
    }
    {
        int total = N_VOX * 8;
        scatter_kernel<<<(total + 255) / 256, 256, 0, stream>>>(coords, feats, vout, cnts, lastidx);
    }
    finalize_verts<<<(N_VERTS + 255) / 256, 256, 0, stream>>>(vout, cnts);
    {
        long total = OUTW_WORDS;
        weights_fill<<<(int)((total + 255) / 256), 256, 0, stream>>>(feats, lastidx, outw);
    }
}

// Round 3
// 347.442 us; speedup vs baseline: 4.6016x; 4.6016x over previous
//
#include <hip/hip_runtime.h>

#define RES 128
#define RES_V 129
#define N_VOX 400000

constexpr int N_VERTS = RES_V * RES_V * RES_V;   // 2146689
constexpr int N_CELLS = RES * RES * RES;         // 2097152
constexpr long VOUT_WORDS = (long)N_VERTS * 10;  // 21466890
constexpr long OUTW_WORDS = (long)N_CELLS * 21;  // 44040192
constexpr int SCAN_BLOCKS = 512;                 // N_CELLS / 4096
constexpr float SDF_BIAS = -1.0f / 128.0f;
constexpr float DEFORM_SCALE = (float)((1.0 - 1e-8) / 256.0);
constexpr float INV_RES = 1.0f / 128.0f;

// --- K0: init cell counts + lastidx ---
__global__ void init_kernel(unsigned int* __restrict__ counts,
                            int* __restrict__ lastidx)
{
    int t = blockIdx.x * blockDim.x + threadIdx.x;
    if (t < N_CELLS) { counts[t] = 0u; lastidx[t] = -1; }
}

// --- K1: per-voxel cell histogram + last-wins index ---
__global__ void count_kernel(const int* __restrict__ coords,
                             unsigned int* __restrict__ counts,
                             int* __restrict__ lastidx)
{
    int n = blockIdx.x * blockDim.x + threadIdx.x;
    if (n >= N_VOX) return;
    int cx = coords[n * 3 + 0];
    int cy = coords[n * 3 + 1];
    int cz = coords[n * 3 + 2];
    int cid = (cx * RES + cy) * RES + cz;
    atomicAdd(counts + cid, 1u);
    atomicMax(lastidx + cid, n);   // numpy .at[].set duplicate = last write wins
}

// --- K2: block-local exclusive scan (4096 elems / block) ---
__global__ void scan1_kernel(const unsigned int* __restrict__ counts,
                             unsigned int* __restrict__ offsets,
                             unsigned int* __restrict__ blocksums)
{
    __shared__ unsigned int part[256];
    int b = blockIdx.x, t = threadIdx.x;
    long base = (long)b * 4096 + (long)t * 16;
    unsigned int v[16], s = 0;
#pragma unroll
    for (int i = 0; i < 16; ++i) { v[i] = counts[base + i]; s += v[i]; }
    part[t] = s;
    __syncthreads();
    for (int off = 1; off < 256; off <<= 1) {
        unsigned int x = (t >= off) ? part[t - off] : 0u;
        __syncthreads();
        part[t] += x;
        __syncthreads();
    }
    unsigned int excl = (t == 0) ? 0u : part[t - 1];
    if (t == 255) blocksums[b] = part[255];
    unsigned int run = excl;
#pragma unroll
    for (int i = 0; i < 16; ++i) { offsets[base + i] = run; run += v[i]; }
}

// --- K3: exclusive scan of the 512 block sums (single block) ---
__global__ void scan2_kernel(unsigned int* __restrict__ blocksums)
{
    __shared__ unsigned int sh[SCAN_BLOCKS];
    int t = threadIdx.x;
    sh[t] = blocksums[t];
    __syncthreads();
    for (int off = 1; off < SCAN_BLOCKS; off <<= 1) {
        unsigned int x = (t >= off) ? sh[t - off] : 0u;
        __syncthreads();
        sh[t] += x;
        __syncthreads();
    }
    blocksums[t] = (t == 0) ? 0u : sh[t - 1];
}

// --- K4: fill CSR lists (offsets become local-end cursors) ---
__global__ void fill_kernel(const int* __restrict__ coords,
                            unsigned int* __restrict__ offsets,   // local-exclusive
                            const unsigned int* __restrict__ blocksums,
                            unsigned int* __restrict__ list)
{
    int n = blockIdx.x * blockDim.x + threadIdx.x;
    if (n >= N_VOX) return;
    int cx = coords[n * 3 + 0];
    int cy = coords[n * 3 + 1];
    int cz = coords[n * 3 + 2];
    int cid = (cx * RES + cy) * RES + cz;
    unsigned int slot = atomicAdd(offsets + cid, 1u) + blocksums[cid >> 12];
    list[slot] = (unsigned int)n;
}

// --- K5: per-vertex gather + mean + finalize (no float atomics) ---
__global__ void gather_finalize(const float* __restrict__ feats,
                                const unsigned int* __restrict__ counts,
                                const unsigned int* __restrict__ offsets_post, // local end
                                const unsigned int* __restrict__ blocksums,
                                const unsigned int* __restrict__ list,
                                float* __restrict__ vout)
{
    int vid = blockIdx.x * blockDim.x + threadIdx.x;
    if (vid >= N_VERTS) return;
    int z = vid % RES_V;
    int tmp = vid / RES_V;
    int y = tmp % RES_V;
    int x = tmp / RES_V;

    float sums[10];
#pragma unroll
    for (int j = 0; j < 10; ++j) sums[j] = 0.0f;
    int cnt = 0;

#pragma unroll
    for (int dx = 0; dx < 2; ++dx) {
        int cx = x - dx;
        if (cx < 0 || cx >= RES) continue;
#pragma unroll
        for (int dy = 0; dy < 2; ++dy) {
            int cy = y - dy;
            if (cy < 0 || cy >= RES) continue;
#pragma unroll
            for (int dz = 0; dz < 2; ++dz) {
                int cz = z - dz;
                if (cz < 0 || cz >= RES) continue;
                int cid = (cx * RES + cy) * RES + cz;
                unsigned int c = counts[cid];
                if (c == 0u) continue;
                unsigned int end = offsets_post[cid] + blocksums[cid >> 12];
                unsigned int start = end - c;
                int cidx = dx + 2 * dy + 4 * dz;
                for (unsigned int i = start; i < end; ++i) {
                    int n = (int)list[i];
                    const float* f = feats + (long)n * 101;
                    sums[0] += f[cidx];
#pragma unroll
                    for (int k = 0; k < 3; ++k) sums[1 + k] += f[8 + 3 * cidx + k];
#pragma unroll
                    for (int k = 0; k < 6; ++k) sums[4 + k] += f[53 + 6 * cidx + k];
                }
                cnt += (int)c;
            }
        }
    }

    float fc = (float)cnt;
    float inv = 1.0f / fmaxf(fc, 1.0f);
    float o[10];
    o[0] = (float)x * INV_RES - 0.5f + DEFORM_SCALE * tanhf(sums[1] * inv);
    o[1] = (float)y * INV_RES - 0.5f + DEFORM_SCALE * tanhf(sums[2] * inv);
    o[2] = (float)z * INV_RES - 0.5f + DEFORM_SCALE * tanhf(sums[3] * inv);
    o[3] = (sums[0] + fc * SDF_BIAS) * inv;   // bias only for actual contributors
#pragma unroll
    for (int j = 0; j < 6; ++j) o[4 + j] = sums[4 + j] * inv;

    float* p = vout + (long)vid * 10;
#pragma unroll
    for (int j = 0; j < 10; ++j) p[j] = o[j];
}

// --- K6: weights grid, one thread per output element (coalesced) ---
__global__ void weights_fill(const float* __restrict__ feats,
                             const int* __restrict__ lastidx,
                             float* __restrict__ outw)
{
    long t = (long)blockIdx.x * blockDim.x + threadIdx.x;
    if (t >= OUTW_WORDS) return;
    int cid = (int)(t / 21);
    int j = (int)(t - (long)cid * 21);
    int li = lastidx[cid];
    float val = 0.0f;
    if (li >= 0) val = feats[(long)li * 101 + 32 + j];
    outw[t] = val;
}

extern "C" void kernel_launch(void* const* d_in, const int* in_sizes, int n_in,
                              void* d_out, int out_size, void* d_ws, size_t ws_size,
                              hipStream_t stream) {
    const int* coords = (const int*)d_in[0];
    const float* feats = (const float*)d_in[1];
    float* out = (float*)d_out;
    float* vout = out;                          // [N_VERTS*10]
    float* outw = out + VOUT_WORDS;             // [N_CELLS*21]

    // d_ws: lastidx (8.4 MB) + blocksums (2 KB) — safely small.
    int* lastidx = (int*)d_ws;
    unsigned int* blocksums = (unsigned int*)((char*)d_ws + sizeof(int) * (size_t)N_CELLS);

    // CSR scratch lives in the TAIL of outw; fully consumed by gather_finalize
    // which runs strictly before weights_fill overwrites outw.
    long scratch_words = 2L * N_CELLS + N_VOX + 16;
    unsigned int* counts  = (unsigned int*)(outw + (OUTW_WORDS - scratch_words));
    unsigned int* offsets = counts + N_CELLS;
    unsigned int* list    = offsets + N_CELLS;

    init_kernel<<<(N_CELLS + 255) / 256, 256, 0, stream>>>(counts, lastidx);
    count_kernel<<<(N_VOX + 255) / 256, 256, 0, stream>>>(coords, counts, lastidx);
    scan1_kernel<<<SCAN_BLOCKS, 256, 0, stream>>>(counts, offsets, blocksums);
    scan2_kernel<<<1, SCAN_BLOCKS, 0, stream>>>(blocksums);
    fill_kernel<<<(N_VOX + 255) / 256, 256, 0, stream>>>(coords, offsets, blocksums, list);
    gather_finalize<<<(N_VERTS + 255) / 256, 256, 0, stream>>>(feats, counts, offsets, blocksums, list, vout);
    {
        long total = OUTW_WORDS;
        weights_fill<<<(int)((total + 255) / 256), 256, 0, stream>>>(feats, lastidx, outw);
    }
}